// Round 10
// baseline (750.663 us; speedup 1.0000x reference)
//
#include <hip/hip_runtime.h>
#include <math.h>

typedef __attribute__((ext_vector_type(8))) short bf16x8;
typedef __attribute__((ext_vector_type(4))) float f32x4;

#define THREADS 256
#define MTILE 48
#define KSTEPS 16

// LDS byte offsets (52 KB total -> up to 3 blocks/CU if regs allow)
#define OFF_HALL  0        // [16 ks][48 row][64 B] = 49152
#define OFF_FEATS 49152    // [48 row][32 f] bf16 = 3072
#define LDS_TOTAL 53248
#define OFF_POOL  0        // [8][512] f32 = 16384, aliases hAll (dead after k-loop)

// RTN-even fp32 -> bf16 bits
__device__ __forceinline__ ushort f2bf(float f) {
    union { float f; uint u; } x; x.f = f;
    uint r = (x.u + 0x7fffu + ((x.u >> 16) & 1u)) >> 16;
    return (ushort)r;
}
__device__ __forceinline__ float bf2f(ushort u) {
    union { uint u; float f; } x; x.u = (uint)u << 16; return x.f;
}

// -------------------------------------------------------------------------
// prep: W2 (512x512 f32, [k][n]) -> w2t bf16 [kt][n][32 k] (natural k order).
// Slot (kt,n) = 64 B; sub-chunk q (0..3) holds k = kt*32 + q*8 .. +7.
// -------------------------------------------------------------------------
__global__ __launch_bounds__(256) void prep_w2(const float* __restrict__ W2,
                                               uint* __restrict__ w2t)
{
    int tid = blockIdx.x * 256 + threadIdx.x;   // 0..8191
    int kt = tid >> 9, n = tid & 511;
    uint* dst = w2t + (size_t)(kt * 512 + n) * 16;
    #pragma unroll
    for (int c = 0; c < 4; ++c) {
        uint qv[4];
        #pragma unroll
        for (int j = 0; j < 4; ++j) {
            int k = kt * 32 + c * 8 + j * 2;
            float f0 = W2[(size_t)k * 512 + n];
            float f1 = W2[(size_t)(k + 1) * 512 + n];
            qv[j] = (uint)f2bf(f0) | ((uint)f2bf(f1) << 16);
        }
        ((uint4*)dst)[c] = make_uint4(qv[0], qv[1], qv[2], qv[3]);
    }
}

// -------------------------------------------------------------------------
// rel: 256 thr / 4 waves; MTILE=48 rows; wave owns 128 exclusive N-cols.
// Layer-1 h via MFMA (W1 A-frags in regs). Main k-loop barrier-free,
// B in a 3-deep register ring (prefetch distance ~2 gsteps), rotated kt
// order. Output via nontemporal stores (keep L2 clean for w2t).
// -------------------------------------------------------------------------
__global__ __launch_bounds__(THREADS, 2) void rel_kernel(
    const float* __restrict__ ctx, const float* __restrict__ W1,
    const float* __restrict__ b1, const uint* __restrict__ w2t,
    const float* __restrict__ b2, const float* __restrict__ Wp,
    const float* __restrict__ bp, float* __restrict__ out, int B)
{
    __shared__ __align__(16) char smem[LDS_TOTAL];
    const int t = threadIdx.x;
    const int wid = t >> 6, l = t & 63;
    const int q = l >> 4, ln = l & 15;
    const int blk = blockIdx.x;
    const int totalG = B * 7;

    const int kt0 = ((blk & 3) * 4 + wid + (blk >> 3)) & 15;
    const char* wbase = (const char*)w2t + (wid * 128 + ln) * 64 + q * 16;

    uint4 b0[8], b1r[8], b2r[8];

#define LOADB(dst, kn)                                                   \
    do {                                                                 \
        _Pragma("unroll")                                                \
        for (int nf = 0; nf < 8; ++nf)                                   \
            dst[nf] = *(const uint4*)(wbase + (kn) * 32768 + nf * 1024); \
    } while (0)

    // ---- prologue B prefetch: ksteps kt0, kt0+1 ----
    LOADB(b0, kt0);
    LOADB(b1r, (kt0 + 1) & 15);

    // ---- stage featsb: bf16 [row][32 f], f 9..31 zero ----
    if (t < MTILE) {
        int R = blk * MTILE + t;
        int G = R / 6, jj = R - G * 6;
        float ff[9];
        if (G < totalG) {
            int b = G / 7, i = G - b * 7;
            int j = jj + (jj >= i ? 1 : 0);
            const float* cb = ctx + (size_t)b * 28;
            float xi0=cb[i*4], xi1=cb[i*4+1], xi2=cb[i*4+2], xi3=cb[i*4+3];
            float xj0=cb[j*4], xj1=cb[j*4+1], xj2=cb[j*4+2], xj3=cb[j*4+3];
            float d0=xi0-xj0, d1=xi1-xj1, d2=xi2-xj2, d3=xi3-xj3;
            ff[0]=xi2; ff[1]=xi3; ff[2]=xj2; ff[3]=xj3;
            ff[4]=d0;  ff[5]=d1;  ff[6]=d2;  ff[7]=d3;
            ff[8]=sqrtf(d0*d0 + d1*d1);
        } else {
            #pragma unroll
            for (int f = 0; f < 9; ++f) ff[f] = 0.f;
        }
        uint pk[16];
        #pragma unroll
        for (int u = 0; u < 16; ++u) pk[u] = 0u;
        #pragma unroll
        for (int f = 0; f < 9; ++f) {
            uint bv = f2bf(ff[f]);
            pk[f >> 1] |= (f & 1) ? (bv << 16) : bv;
        }
        uint4* dst = (uint4*)(smem + OFF_FEATS + t * 64);
        dst[0] = make_uint4(pk[0],  pk[1],  pk[2],  pk[3]);
        dst[1] = make_uint4(pk[4],  pk[5],  pk[6],  pk[7]);
        dst[2] = make_uint4(pk[8],  pk[9],  pk[10], pk[11]);
        dst[3] = make_uint4(pk[12], pk[13], pk[14], pk[15]);
    }
    __syncthreads();

    // ---- layer-1 via MFMA (swapped): D[k_h][row] = W1^T . feats^T ----
    {
        bf16x8 fb[3];
        #pragma unroll
        for (int rt = 0; rt < 3; ++rt)
            fb[rt] = *(const bf16x8*)(smem + OFF_FEATS + (rt*16 + ln)*64 + q*16);
        #pragma unroll
        for (int a = 0; a < 8; ++a) {
            int kt16 = wid * 8 + a;
            int kh = kt16 * 16 + ln;
            uint aw[4];
            #pragma unroll
            for (int jj2 = 0; jj2 < 4; ++jj2) {
                int f0 = q * 8 + jj2 * 2, f1 = f0 + 1;
                uint lo = (f0 < 9) ? (uint)f2bf(W1[f0 * 512 + kh]) : 0u;
                uint hi = (f1 < 9) ? (uint)f2bf(W1[f1 * 512 + kh]) : 0u;
                aw[jj2] = lo | (hi << 16);
            }
            bf16x8 wa;
            { uint4 tmp = make_uint4(aw[0], aw[1], aw[2], aw[3]);
              wa = *(bf16x8*)&tmp; }
            float4 bb = *(const float4*)(b1 + kt16 * 16 + q * 4);
            #pragma unroll
            for (int rt = 0; rt < 3; ++rt) {
                f32x4 d = __builtin_amdgcn_mfma_f32_16x16x32_bf16(
                    wa, fb[rt], (f32x4){0.f,0.f,0.f,0.f}, 0, 0, 0);
                uint p0 = (uint)f2bf(fmaxf(d[0]+bb.x, 0.f))
                        | ((uint)f2bf(fmaxf(d[1]+bb.y, 0.f)) << 16);
                uint p1 = (uint)f2bf(fmaxf(d[2]+bb.z, 0.f))
                        | ((uint)f2bf(fmaxf(d[3]+bb.w, 0.f)) << 16);
                int row = rt*16 + ln;
                char* dst = smem + OFF_HALL + (kt16 >> 1)*3072 + row*64
                          + (kt16 & 1)*32 + q*8;
                *(uint2*)dst = make_uint2(p0, p1);
            }
        }
    }
    __syncthreads();

    // ---- main k-loop: barrier-free; 3-deep B ring, 2-gstep prefetch dist
    f32x4 acc[3][8];
    #pragma unroll
    for (int mf = 0; mf < 3; ++mf)
        #pragma unroll
        for (int nf = 0; nf < 8; ++nf)
            acc[mf][nf] = (f32x4){0.f, 0.f, 0.f, 0.f};

    int aoff[3];
    #pragma unroll
    for (int mf = 0; mf < 3; ++mf)
        aoff[mf] = OFF_HALL + (mf*16 + ln)*64 + q*16;

#define GSTEP(ks, bf)                                                         \
    do {                                                                      \
        bf16x8 a0 = *(const bf16x8*)(smem + aoff[0] + (ks)*3072);             \
        bf16x8 a1 = *(const bf16x8*)(smem + aoff[1] + (ks)*3072);             \
        bf16x8 a2 = *(const bf16x8*)(smem + aoff[2] + (ks)*3072);             \
        _Pragma("unroll")                                                     \
        for (int nf = 0; nf < 8; ++nf) {                                      \
            bf16x8 w = *(const bf16x8*)&bf[nf];                               \
            acc[0][nf] = __builtin_amdgcn_mfma_f32_16x16x32_bf16(a0, w, acc[0][nf], 0,0,0); \
            acc[1][nf] = __builtin_amdgcn_mfma_f32_16x16x32_bf16(a1, w, acc[1][nf], 0,0,0); \
            acc[2][nf] = __builtin_amdgcn_mfma_f32_16x16x32_bf16(a2, w, acc[2][nf], 0,0,0); \
        }                                                                     \
    } while (0)

    #pragma unroll
    for (int s = 0; s < KSTEPS; ++s) {
        // issue loads for s+2 first (into the buffer consumed at s-1)
        if (s + 2 < KSTEPS) {
            int kn = (kt0 + s + 2) & 15;
            switch ((s + 2) % 3) {
                case 0: LOADB(b0, kn); break;
                case 1: LOADB(b1r, kn); break;
                default: LOADB(b2r, kn); break;
            }
        }
        int kc = (kt0 + s) & 15;
        switch (s % 3) {
            case 0: GSTEP(kc, b0); break;
            case 1: GSTEP(kc, b1r); break;
            default: GSTEP(kc, b2r); break;
        }
    }

    // ---- epilogue: +b2, relu, mean over 6 j's via LDS pool atomics ----
    __syncthreads();                     // all hAll reads done; pool aliases it
    float* pool = (float*)(smem + OFF_POOL);
    #pragma unroll
    for (int i = 0; i < 4; ++i)
        ((float4*)pool)[t + i*256] = make_float4(0.f, 0.f, 0.f, 0.f);
    __syncthreads();

    const float inv6 = 1.0f / 6.0f;
    #pragma unroll
    for (int mf = 0; mf < 3; ++mf) {
        int rbase = mf*16 + q*4;
        #pragma unroll
        for (int nf = 0; nf < 8; ++nf) {
            int col = wid*128 + nf*16 + ln;
            float bbv = b2[col];
            f32x4 a = acc[mf][nf];
            float run = 0.f;
            int gprev = rbase / 6;
            #pragma unroll
            for (int r = 0; r < 4; ++r) {
                int g = (rbase + r) / 6;
                float vv = fmaxf(a[r] + bbv, 0.f) * inv6;
                if (g != gprev) {
                    atomicAdd(pool + gprev*512 + col, run);
                    run = 0.f; gprev = g;
                }
                run += vv;
            }
            atomicAdd(pool + gprev*512 + col, run);
        }
    }
    __syncthreads();

    // ---- store: rel half from pool, prop half inline; nontemporal f32x4 ----
    #pragma unroll
    for (int i = 0; i < 4; ++i) {
        int e = t + i*256;               // float4 slot, 1024 total = 8 grp x 128
        int g = e >> 7, c4 = e & 127;
        int G = blk * 8 + g;
        if (G < totalG) {
            f32x4 v = ((f32x4*)pool)[e];
            __builtin_nontemporal_store(v, (f32x4*)(out + (size_t)G*1024 + 512 + c4*4));

            ushort u0 = *(const ushort*)(smem + OFF_FEATS + (g*6)*64 + 0);
            ushort u1 = *(const ushort*)(smem + OFF_FEATS + (g*6)*64 + 2);
            float a0 = bf2f(u0), a1 = bf2f(u1);
            float4 w0 = ((const float4*)Wp)[c4];
            float4 w1 = ((const float4*)(Wp + 512))[c4];
            float4 bv = ((const float4*)bp)[c4];
            f32x4 p;
            p[0] = fmaxf(fmaf(a1, w1.x, fmaf(a0, w0.x, bv.x)), 0.f);
            p[1] = fmaxf(fmaf(a1, w1.y, fmaf(a0, w0.y, bv.y)), 0.f);
            p[2] = fmaxf(fmaf(a1, w1.z, fmaf(a0, w0.z, bv.z)), 0.f);
            p[3] = fmaxf(fmaf(a1, w1.w, fmaf(a0, w0.w, bv.w)), 0.f);
            __builtin_nontemporal_store(p, (f32x4*)(out + (size_t)G*1024 + c4*4));
        }
    }
#undef LOADB
#undef GSTEP
}

extern "C" void kernel_launch(void* const* d_in, const int* in_sizes, int n_in,
                              void* d_out, int out_size, void* d_ws, size_t ws_size,
                              hipStream_t stream) {
    const float* ctx = (const float*)d_in[0];
    const float* W1  = (const float*)d_in[1];
    const float* b1  = (const float*)d_in[2];
    const float* W2  = (const float*)d_in[3];
    const float* b2  = (const float*)d_in[4];
    const float* Wp  = (const float*)d_in[5];
    const float* bp  = (const float*)d_in[6];
    float* out = (float*)d_out;

    int B = in_sizes[0] / 28;
    prep_w2<<<32, 256, 0, stream>>>(W2, (uint*)d_ws);   // 512 KB in d_ws

    int blocks = (B * 42 + MTILE - 1) / MTILE;
    rel_kernel<<<blocks, THREADS, 0, stream>>>(ctx, W1, b1, (const uint*)d_ws,
                                               b2, Wp, bp, out, B);
}